// Round 6
// baseline (178.042 us; speedup 1.0000x reference)
//
#include <hip/hip_runtime.h>
#include <hip/hip_bf16.h>

// SizeInvBlock: upsample3x(nearest) -> per-sample dilated 3x3 conv -> maxpool3 -> BN(train) -> relu
// Factorization: conv on the 3x-upsampled image only samples original 32x32 pixels:
//   out[o,y,x] = bias[o] + sum_{ki,kj} T[kikj][o, r_ki(y), c_kj(x)]
//   T[kikj][o,i,j] = sum_c W[o,c,ki,kj] * X[c,i,j]
// R10: gather specialized on (dh%3, dw%3) -> 9 compile-time cases (verified).
// R11 (FAILED): cooperative k2+k3 fusion -> launch rejected. Reverted.
// R12: bf16 LDS staging (28.6KB) -> occupancy 63%, conflicts halved (verified).
// R13/R14: GEMM fused into k2, 1 o/block. GEMM phase = 1 GB L2 traffic
//   (128 blocks re-read each 128KB X_b) = ~31us at the 32 TB/s L2 ceiling.
//   L2-BW-bound; R14's latency/ILP fix was the wrong regime -> regressed.
// R15: 8 o's per block (grid 1024 = 16 og x 64 b, XCD-swizzled so same-b
//   blocks share an XCD's L2). B-frags loaded ONCE into 64 VGPR and reused
//   across the o-loop: X L2 traffic 1GB -> 128MB. Per o: A-frags (tiny,
//   L2-hot) + 16 MFMA + LDS planes + verified gather. __launch_bounds__(512,4)
//   caps VGPR at 128 (2 blocks/CU, ~50% occ).
//
// ws layout (bytes):
//   [0,      1024)    stats: sum[128], sumsq[128] (f32, atomic; zeroed by k0_all)
//   [1024,   3072)    prm: per-b gather params int[64][8] = {g0,g2,f0,f2,case,...}
//   [4096,   151552)  A2 bf16 [128 o][9 kk][64 c]
//   [151552, 8540160) Xc bf16 [64 b][8 c-octet][1024 px][8 c]

typedef __attribute__((ext_vector_type(8))) short bf16x8;
typedef __attribute__((ext_vector_type(4))) float f32x4;
typedef __attribute__((ext_vector_type(8))) unsigned short us8;

__device__ __forceinline__ unsigned short f2bf(float f) {
    unsigned u = __float_as_uint(f);
    u += 0x7fffu + ((u >> 16) & 1u);
    return (unsigned short)(u >> 16);
}
__device__ __forceinline__ float bf2f(unsigned short s) {
    return __uint_as_float(((unsigned)s) << 16);
}
__device__ __forceinline__ int floordiv3(int t) {
    return (t >= 0) ? (t / 3) : -((2 - t) / 3);
}

// ---- K0: merged prep: X repack->bf16 (octet-major), A2 pack, stats, prm --
// blocks 0..1023: Xc; 1024..1311: A2; 1312: stats zero + per-b gather params.
__global__ __launch_bounds__(256) void k0_all(const float* __restrict__ x,
                                              const float* __restrict__ w,
                                              const int* __restrict__ hh,
                                              const int* __restrict__ ww,
                                              unsigned short* __restrict__ xc,
                                              unsigned short* __restrict__ A2,
                                              float* __restrict__ stats,
                                              int* __restrict__ prm) {
    const int bid = blockIdx.x;
    const int tid = threadIdx.x;
    if (bid < 1024) {
        const int n = (bid & 15) * 64 + (tid & 63);
        const int cg = tid >> 6;
        const int b = bid >> 4;
        #pragma unroll
        for (int j2 = 0; j2 < 2; ++j2) {
            int c8 = cg * 2 + j2;                 // 0..7
            us8 r;
            #pragma unroll
            for (int j = 0; j < 8; ++j)
                r[j] = f2bf(x[(((b << 6) + c8 * 8 + j) << 10) + n]);
            // Xc[b][c8][n][8]
            *reinterpret_cast<us8*>(xc + ((size_t)(b * 8 + c8) * 1024 + n) * 8) = r;
        }
    } else if (bid < 1312) {
        int gid = (bid - 1024) * 256 + tid;       // < 73728
        // A2 layout [o][kk][c]: gid = (o*9 + kk)*64 + c
        int m = gid >> 6, c = gid & 63;
        int o = m / 9, kk = m - o * 9;
        A2[gid] = f2bf(w[(o * 64 + c) * 9 + kk]);
    } else {
        stats[tid] = 0.f;                          // 256 floats = sum+sumsq
        if (tid < 64) {
            int dh = 96 / hh[tid]; if (dh < 1) dh = 1;
            int dw = 96 / ww[tid]; if (dw < 1) dw = 1;
            int* p = prm + tid * 8;
            p[0] = floordiv3(-dh);                 // g0
            p[1] = floordiv3(dh);                  // g2
            p[2] = floordiv3(-dw);                 // f0
            p[3] = floordiv3(dw);                  // f2
            p[4] = (dh % 3) * 3 + (dw % 3);        // template case
        }
    }
}

// ---- K2 (fused GEMM + gather, 8 o's/block): B-frags in regs once, per-o
// MFMA T-slice -> LDS bf16 planes -> 36-tap gather + maxpool3 + bias + stats.
// LDS: 9 planes of 33 rows x 48 bf16 (8-col pads both sides, row 32 = zeros).
#define PLSB (33 * 48)

template<int RH, int RW>
__device__ __forceinline__ float gather_half(const unsigned short* __restrict__ lt,
                                             int p, int qoff,
                                             int g0, int g2, int f0, int f2) {
    // per-y3 / per-x3 selector patterns, keyed by (d mod 3):
    //   sel0[t] = floordiv3(t-d)-floordiv3(-d), sel2[t] = floordiv3(t+d)-floordiv3(d)
    constexpr int C0s[3][3] = {{0,0,0},{0,1,1},{0,0,1}};
    constexpr int C2s[3][3] = {{0,0,0},{0,0,1},{0,1,1}};
    constexpr int R0s[3][3] = {{0,0,0},{0,1,1},{0,0,1}};
    constexpr int R2s[3][3] = {{0,0,0},{0,0,1},{0,1,1}};
    constexpr int NR = RH ? 3 : 1;     // distinct row combos
    constexpr int NC = RW ? 3 : 1;     // distinct col combos
    constexpr bool RB = (RH != 0);     // need second-row variant at all?
    constexpr bool CB = (RW != 0);     // need b-columns at all?

    int rA0 = p + g0;     rA0 = ((unsigned)rA0 < 32u) ? rA0 : 32;
    int rA2 = p + g2;     rA2 = ((unsigned)rA2 < 32u) ? rA2 : 32;
    int rB0 = 0, rB2 = 0;
    if (RB) {
        rB0 = p + g0 + 1; rB0 = ((unsigned)rB0 < 32u) ? rB0 : 32;
        rB2 = p + g2 + 1; rB2 = ((unsigned)rB2 < 32u) ? rB2 : 32;
    }

    float u0[2][3], u1[3], u2[2][3];
    {   // ki = 0 (planes 0..2), rows rA0 (+rB0)
        const unsigned short* pl0 = &lt[0 * PLSB + qoff + f0];
        const unsigned short* pl1 = &lt[1 * PLSB + qoff];
        const unsigned short* pl2 = &lt[2 * PLSB + qoff + f2];
        float pA0a = bf2f(pl0[rA0 * 48]), pA0b = CB ? bf2f(pl0[rA0 * 48 + 1]) : 0.f;
        float sA   = bf2f(pl1[rA0 * 48]);
        float pA2a = bf2f(pl2[rA0 * 48]), pA2b = CB ? bf2f(pl2[rA0 * 48 + 1]) : 0.f;
        float pB0a = 0.f, pB0b = 0.f, sB = 0.f, pB2a = 0.f, pB2b = 0.f;
        if (RB) {
            pB0a = bf2f(pl0[rB0 * 48]); pB0b = CB ? bf2f(pl0[rB0 * 48 + 1]) : 0.f;
            sB   = bf2f(pl1[rB0 * 48]);
            pB2a = bf2f(pl2[rB0 * 48]); pB2b = CB ? bf2f(pl2[rB0 * 48 + 1]) : 0.f;
        }
        #pragma unroll
        for (int c = 0; c < NC; ++c) {
            u0[0][c] = (C0s[RW][c] ? pA0b : pA0a) + sA + (C2s[RW][c] ? pA2b : pA2a);
            if (RB)
                u0[1][c] = (C0s[RW][c] ? pB0b : pB0a) + sB + (C2s[RW][c] ? pB2b : pB2a);
        }
    }
    {   // ki = 1 (planes 3..5), row p only (selector identically 0)
        const unsigned short* pl0 = &lt[3 * PLSB + qoff + f0];
        const unsigned short* pl1 = &lt[4 * PLSB + qoff];
        const unsigned short* pl2 = &lt[5 * PLSB + qoff + f2];
        float pa = bf2f(pl0[p * 48]), pb = CB ? bf2f(pl0[p * 48 + 1]) : 0.f;
        float s  = bf2f(pl1[p * 48]);
        float ra = bf2f(pl2[p * 48]), rb = CB ? bf2f(pl2[p * 48 + 1]) : 0.f;
        #pragma unroll
        for (int c = 0; c < NC; ++c)
            u1[c] = (C0s[RW][c] ? pb : pa) + s + (C2s[RW][c] ? rb : ra);
    }
    {   // ki = 2 (planes 6..8), rows rA2 (+rB2)
        const unsigned short* pl0 = &lt[6 * PLSB + qoff + f0];
        const unsigned short* pl1 = &lt[7 * PLSB + qoff];
        const unsigned short* pl2 = &lt[8 * PLSB + qoff + f2];
        float pA0a = bf2f(pl0[rA2 * 48]), pA0b = CB ? bf2f(pl0[rA2 * 48 + 1]) : 0.f;
        float sA   = bf2f(pl1[rA2 * 48]);
        float pA2a = bf2f(pl2[rA2 * 48]), pA2b = CB ? bf2f(pl2[rA2 * 48 + 1]) : 0.f;
        float pB0a = 0.f, pB0b = 0.f, sB = 0.f, pB2a = 0.f, pB2b = 0.f;
        if (RB) {
            pB0a = bf2f(pl0[rB2 * 48]); pB0b = CB ? bf2f(pl0[rB2 * 48 + 1]) : 0.f;
            sB   = bf2f(pl1[rB2 * 48]);
            pB2a = bf2f(pl2[rB2 * 48]); pB2b = CB ? bf2f(pl2[rB2 * 48 + 1]) : 0.f;
        }
        #pragma unroll
        for (int c = 0; c < NC; ++c) {
            u2[0][c] = (C0s[RW][c] ? pA0b : pA0a) + sA + (C2s[RW][c] ? pA2b : pA2a);
            if (RB)
                u2[1][c] = (C0s[RW][c] ? pB0b : pB0a) + sB + (C2s[RW][c] ? pB2b : pB2a);
        }
    }

    float best = -3.4e38f;
    #pragma unroll
    for (int r = 0; r < NR; ++r)
        #pragma unroll
        for (int c = 0; c < NC; ++c) {
            float s = u0[R0s[RH][r]][c] + u1[c] + u2[R2s[RH][r]][c];
            best = fmaxf(best, s);
        }
    return best;
}

// o-loop body for one (og,b) block: B-frags (held in regs by caller scope)
// -> per-o {A-frags, 16 MFMA, LDS planes, sync, gather, stats, sync}.
template<int RH, int RW>
__device__ __forceinline__ void run_og(const unsigned short* __restrict__ A2,
                                       const float* __restrict__ bias,
                                       float* __restrict__ out,
                                       float* __restrict__ stats,
                                       unsigned short* lt, float* red,
                                       const bf16x8 (&bF0)[8], const bf16x8 (&bF1)[8],
                                       int tid, int og, int b,
                                       int g0, int g2, int f0, int f2) {
    const int wave = tid >> 6, lane = tid & 63;
    const int quad = lane >> 4, l15 = lane & 15;
    const int ar = (l15 < 9) ? l15 : 8;            // clamp: rows 9..15 unused
    const int q = tid & 31, pbase = tid >> 5;      // pbase 0..15
    const int qoff = q + 8;

    for (int oi = 0; oi < 8; ++oi) {
        const int o = og * 8 + oi;
        const unsigned short* A2o = A2 + o * 576;  // [9 kk][64 c]
        const bf16x8 aF0 = *reinterpret_cast<const bf16x8*>(A2o + ar * 64 + quad * 8);
        const bf16x8 aF1 = *reinterpret_cast<const bf16x8*>(A2o + ar * 64 + 32 + quad * 8);
        #pragma unroll
        for (int i = 0; i < 8; ++i) {
            f32x4 acc = {};
            acc = __builtin_amdgcn_mfma_f32_16x16x32_bf16(aF0, bF0[i], acc, 0, 0, 0);
            acc = __builtin_amdgcn_mfma_f32_16x16x32_bf16(aF1, bF1[i], acc, 0, 0, 0);
            // D: col px = wave*128 + i*16 + l15, rows kk = quad*4 + r (kk < 9)
            const int px = wave * 128 + i * 16 + l15;
            const int base = (px >> 5) * 48 + (px & 31) + 8;
            #pragma unroll
            for (int r = 0; r < 4; ++r) {
                const int kk = quad * 4 + r;
                if (kk < 9)
                    lt[kk * PLSB + base] = f2bf(acc[r]);
            }
        }
        __syncthreads();   // planes complete (pads were zeroed before 1st o)

        float v0 = gather_half<RH, RW>(lt, pbase,      qoff, g0, g2, f0, f2);
        float v1 = gather_half<RH, RW>(lt, pbase + 16, qoff, g0, g2, f0, f2);
        const float bias_o = bias[o];
        const float val0 = v0 + bias_o;
        const float val1 = v1 + bias_o;
        out[(((size_t)b * 128 + o) * 32 + pbase) * 32 + q] = val0;
        out[(((size_t)b * 128 + o) * 32 + pbase + 16) * 32 + q] = val1;
        float s1 = val0 + val1;
        float s2 = val0 * val0 + val1 * val1;

        // stats: wave reduce -> LDS -> block reduce -> 2 atomics
        #pragma unroll
        for (int m = 32; m >= 1; m >>= 1) {
            s1 += __shfl_xor(s1, m, 64);
            s2 += __shfl_xor(s2, m, 64);
        }
        if ((tid & 63) == 0) {
            red[tid >> 6] = s1;
            red[8 + (tid >> 6)] = s2;
        }
        __syncthreads();   // red visible; all lt reads of this o complete
        if (tid < 64) {
            float a1 = (tid < 8) ? red[tid] : 0.f;
            float a2 = (tid < 8) ? red[8 + tid] : 0.f;
            #pragma unroll
            for (int m = 4; m >= 1; m >>= 1) {
                a1 += __shfl_xor(a1, m, 64);
                a2 += __shfl_xor(a2, m, 64);
            }
            if (tid == 0) {
                atomicAdd(&stats[o], a1);
                atomicAdd(&stats[128 + o], a2);
            }
        }
        // next o's lt writes are safe (all lt reads precede the sync above);
        // next red write is ordered by next iteration's first sync.
    }
}

__global__ __launch_bounds__(512, 4) void k2_fused(const unsigned short* __restrict__ Xc,
                                                   const unsigned short* __restrict__ A2,
                                                   const float* __restrict__ bias,
                                                   const int* __restrict__ prm,
                                                   float* __restrict__ out,
                                                   float* __restrict__ stats) {
    __shared__ __align__(16) unsigned short lt[9 * PLSB + 8];
    __shared__ float red[16];
    const int tid = threadIdx.x;
    // bijective XCD swizzle: bids == k (mod 8) run on XCD k; give each XCD a
    // contiguous swz range => all 16 same-b blocks share one XCD's L2.
    const int bid = blockIdx.x;                    // 0..1023
    const int swz = (bid & 7) * 128 + (bid >> 3);
    const int og = swz & 15, b = swz >> 4;         // og 0..15, b 0..63

    // ---- load all 16 B-frags once (held in regs across the whole o-loop) --
    const int wave = tid >> 6, lane = tid & 63;
    const int quad = lane >> 4, l15 = lane & 15;
    const unsigned short* Xb = Xc + (size_t)b * 65536; // [8 oct][1024 px][8]
    const unsigned short* xbase = Xb + ((size_t)quad * 1024 + wave * 128 + l15) * 8;
    bf16x8 bF0[8], bF1[8];
    #pragma unroll
    for (int i = 0; i < 8; ++i) {
        const unsigned short* xp = xbase + i * 128;    // (i*16 px) * 8
        bF0[i] = *reinterpret_cast<const bf16x8*>(xp);
        bF1[i] = *reinterpret_cast<const bf16x8*>(xp + 32768);
    }

    // ---- zero pads once (GEMM only writes interior cols 8..39, rows 0..31) -
    static const us8 z8 = {0, 0, 0, 0, 0, 0, 0, 0};
    {
        int i = tid;                               // 0..511
        int kk = i >> 6, rem = i & 63, r = rem >> 1, side = rem & 1;
        *reinterpret_cast<us8*>(&lt[kk * PLSB + r * 48 + side * 40]) = z8;
        if (tid < 64) {
            i = tid + 512;                         // 512..575
            kk = i >> 6; rem = i & 63; r = rem >> 1; side = rem & 1;
            *reinterpret_cast<us8*>(&lt[kk * PLSB + r * 48 + side * 40]) = z8;
        }
    }
    if (tid < 54) {                                // row 32 of each plane
        int kk = tid / 6, c = tid - kk * 6;
        *reinterpret_cast<us8*>(&lt[kk * PLSB + 32 * 48 + c * 8]) = z8;
    }
    if (tid == 63) *reinterpret_cast<us8*>(&lt[9 * PLSB]) = z8;

    // block-uniform gather params (precomputed in k0, scalar loads)
    const int* pb = prm + b * 8;
    const int g0 = pb[0], g2 = pb[1], f0 = pb[2], f2 = pb[3], cs = pb[4];

    #define GCASE(n) case n: \
        run_og<(n)/3, (n)%3>(A2, bias, out, stats, lt, red, bF0, bF1, \
                             tid, og, b, g0, g2, f0, f2); \
        break;
    switch (cs) {
        GCASE(0) GCASE(1) GCASE(2) GCASE(3)
        GCASE(4) GCASE(5) GCASE(6) GCASE(7)
        default:
            run_og<2, 2>(A2, bias, out, stats, lt, red, bF0, bF1,
                         tid, og, b, g0, g2, f0, f2);
            break;
    }
    #undef GCASE
}

// ---- K3: BN finalize + affine + relu, in-place on d_out ------------------
__global__ __launch_bounds__(256) void k3_bn(float4* __restrict__ out,
                                             const float* __restrict__ stats,
                                             const float* __restrict__ gamma,
                                             const float* __restrict__ beta) {
    int i4 = blockIdx.x * 256 + threadIdx.x;   // 0..2097151
    int o = (i4 >> 8) & 127;
    const float invN = 1.0f / 65536.0f;
    float mean = stats[o] * invN;
    float var = stats[128 + o] * invN - mean * mean;
    float inv = rsqrtf(var + 1e-5f);
    float sc = gamma[o] * inv;
    float sh = beta[o] - mean * sc;
    float4 v = out[i4];
    v.x = fmaxf(fmaf(v.x, sc, sh), 0.f);
    v.y = fmaxf(fmaf(v.y, sc, sh), 0.f);
    v.z = fmaxf(fmaf(v.z, sc, sh), 0.f);
    v.w = fmaxf(fmaf(v.w, sc, sh), 0.f);
    out[i4] = v;
}

extern "C" void kernel_launch(void* const* d_in, const int* in_sizes, int n_in,
                              void* d_out, int out_size, void* d_ws, size_t ws_size,
                              hipStream_t stream) {
    const float* x     = (const float*)d_in[0];
    const int*   h     = (const int*)d_in[1];
    const int*   w     = (const int*)d_in[2];
    const float* wt    = (const float*)d_in[3];
    const float* bias  = (const float*)d_in[4];
    const float* gamma = (const float*)d_in[5];
    const float* beta  = (const float*)d_in[6];
    float* out = (float*)d_out;
    char* ws = (char*)d_ws;

    float*          stats = (float*)(ws + 0);
    int*            prm   = (int*)(ws + 1024);
    unsigned short* A2    = (unsigned short*)(ws + 4096);
    unsigned short* Xc    = (unsigned short*)(ws + 151552);

    k0_all<<<1313, 256, 0, stream>>>(x, wt, h, w, Xc, A2, stats, prm);
    k2_fused<<<1024, 512, 0, stream>>>(Xc, A2, bias, prm, out, stats);
    k3_bn<<<8192, 256, 0, stream>>>((float4*)out, stats, gamma, beta);
}

// Round 7
// 150.911 us; speedup vs baseline: 1.1798x; 1.1798x over previous
//
#include <hip/hip_runtime.h>
#include <hip/hip_bf16.h>

// SizeInvBlock: upsample3x(nearest) -> per-sample dilated 3x3 conv -> maxpool3 -> BN(train) -> relu
// Factorization: conv on the 3x-upsampled image only samples original 32x32 pixels:
//   out[o,y,x] = bias[o] + sum_{ki,kj} T[kikj][o, r_ki(y), c_kj(x)]
//   T[kikj][o,i,j] = sum_c W[o,c,ki,kj] * X[c,i,j]   (one GEMM, 9x fewer FLOPs than direct conv)
// R10: gather specialized on (dh%3, dw%3) -> 9 compile-time cases (verified).
// R11 (FAILED): cooperative k2+k3 fusion -> launch rejected. Reverted.
// R12: bf16 LDS staging (28.6KB) -> occupancy 63%, conflicts halved (verified, 152.8us).
// R13/R14/R15 (FAILED x3): GEMM fused into k2 (1 o/block, +ILP, 8 o/block):
//   78/87/92us vs split 47+~24. Per-block M=9 GEMM is VALU/latency-inefficient;
//   saved HBM bytes don't matter (not BW-bound). Fused direction abandoned.
// R16: revert to R12/R3 split structure + bf16 k2->k3 intermediate:
//   k2 writes pre-BN vals as bf16 (16.8MB) into ws scratch (after T; runtime
//   ws_size guard, f32 in-place path as fallback), k3 reads bf16 + writes f32
//   out once. Saves ~33MB HBM. Quantization ~0.02 absmax, threshold 0.1125.
//
// ws layout (bytes):
//   [0,      1024)    stats: sum[128], sumsq[128] (f32, atomic; zeroed by k0_all)
//   [1024,   3072)    prm: per-b gather params int[64][8] = {g0,g2,f0,f2,case,...}
//   [4096,   151552)  A bf16 [1152][64]   (m = (ki*3+kj)*128 + o, k = cin)
//   [151552, 8540160) XbT bf16 [64 b][1024 n][64 c]
//   [8540160,159535104) T bf16 [1152][65536]  (n = b*1024 + i*32 + j)
//   [159535104, 176312320) tout bf16 [64 b][128 o][32][32]  (only if ws_size allows)

typedef __attribute__((ext_vector_type(8))) short bf16x8;
typedef __attribute__((ext_vector_type(4))) float f32x4;
typedef __attribute__((ext_vector_type(8))) unsigned short us8;
typedef __attribute__((ext_vector_type(4))) unsigned short us4;

#define BN 65536   // T n-dimension (all 64 samples)

__device__ __forceinline__ unsigned short f2bf(float f) {
    unsigned u = __float_as_uint(f);
    u += 0x7fffu + ((u >> 16) & 1u);
    return (unsigned short)(u >> 16);
}
__device__ __forceinline__ float bf2f(unsigned short s) {
    return __uint_as_float(((unsigned)s) << 16);
}
__device__ __forceinline__ int floordiv3(int t) {
    return (t >= 0) ? (t / 3) : -((2 - t) / 3);
}

// ---- K0: merged prep: X transpose->bf16, W pack->bf16, stats zero, prm ---
// blocks 0..1023: XbT; 1024..1311: A; 1312: stats zero + per-b gather params.
__global__ __launch_bounds__(256) void k0_all(const float* __restrict__ x,
                                              const float* __restrict__ w,
                                              const int* __restrict__ hh,
                                              const int* __restrict__ ww,
                                              unsigned short* __restrict__ xbt,
                                              unsigned short* __restrict__ A,
                                              float* __restrict__ stats,
                                              int* __restrict__ prm) {
    const int bid = blockIdx.x;
    const int tid = threadIdx.x;
    if (bid < 1024) {
        const int n = (bid & 15) * 64 + (tid & 63);
        const int cg = tid >> 6;
        const int b = bid >> 4;
        #pragma unroll
        for (int j2 = 0; j2 < 2; ++j2) {
            int c8 = cg * 2 + j2;                 // 0..7
            us8 r;
            #pragma unroll
            for (int j = 0; j < 8; ++j)
                r[j] = f2bf(x[(((b << 6) + c8 * 8 + j) << 10) + n]);
            *reinterpret_cast<us8*>(xbt + ((size_t)(b << 10) + n) * 64 + c8 * 8) = r;
        }
    } else if (bid < 1312) {
        int gid = (bid - 1024) * 256 + tid;       // < 73728
        int m = gid >> 6, c = gid & 63;
        int kk = m >> 7, o = m & 127;
        A[gid] = f2bf(w[(o * 64 + c) * 9 + kk]);
    } else {
        stats[tid] = 0.f;                          // 256 floats = sum+sumsq
        if (tid < 64) {
            int dh = 96 / hh[tid]; if (dh < 1) dh = 1;
            int dw = 96 / ww[tid]; if (dw < 1) dw = 1;
            int* p = prm + tid * 8;
            p[0] = floordiv3(-dh);                 // g0
            p[1] = floordiv3(dh);                  // g2
            p[2] = floordiv3(-dw);                 // f0
            p[3] = floordiv3(dw);                  // f2
            p[4] = (dh % 3) * 3 + (dw % 3);        // template case
        }
    }
}

// ---- K1: GEMM A[1152x64] @ XbT^T[64 x 65536] -> T bf16 (R5 verbatim) -----
// grid (512 nt, 9 mt), 256 thr (2x2 wave grid), tile 128m x 128n, K=64.
__global__ __launch_bounds__(256) void k1_gemm(const unsigned short* __restrict__ XbT,
                                               const unsigned short* __restrict__ A,
                                               unsigned short* __restrict__ T) {
    __shared__ union {
        struct { us8 lA[8 * 129]; us8 lB[8 * 129]; } in;   // 33024 B
        unsigned short ot[128 * 132];                       // 33792 B
    } sm;
    const int tid = threadIdx.x;
    const int nt = blockIdx.x;    // 0..511
    const int mt = blockIdx.y;    // 0..8

    #pragma unroll
    for (int i = 0; i < 4; ++i) {
        int gid = i * 256 + tid;
        int row = gid >> 3, ch = gid & 7; // ch fastest -> coalesced 16B/lane
        sm.in.lA[ch * 129 + row] = *reinterpret_cast<const us8*>(
            A + (size_t)(mt * 128 + row) * 64 + ch * 8);
    }
    #pragma unroll
    for (int i = 0; i < 4; ++i) {
        int gid = i * 256 + tid;
        int row = gid >> 3, ch = gid & 7;
        sm.in.lB[ch * 129 + row] = *reinterpret_cast<const us8*>(
            XbT + ((size_t)nt * 128 + row) * 64 + ch * 8);
    }
    __syncthreads();

    const int wave = tid >> 6, lane = tid & 63;
    const int quad = lane >> 4, l15 = lane & 15;
    const int wm = wave & 1, wn = wave >> 1;
    const bf16x8* pA = reinterpret_cast<const bf16x8*>(sm.in.lA);
    const bf16x8* pB = reinterpret_cast<const bf16x8*>(sm.in.lB);

    f32x4 acc[4][4] = {};
    #pragma unroll
    for (int ks = 0; ks < 2; ++ks) {
        const int kg = ks * 4 + quad;
        bf16x8 aF[4], bF[4];
        #pragma unroll
        for (int mi = 0; mi < 4; ++mi)
            aF[mi] = pA[kg * 129 + wm * 64 + mi * 16 + l15];
        #pragma unroll
        for (int ni = 0; ni < 4; ++ni)
            bF[ni] = pB[kg * 129 + wn * 64 + ni * 16 + l15];
        #pragma unroll
        for (int mi = 0; mi < 4; ++mi)
            #pragma unroll
            for (int ni = 0; ni < 4; ++ni)
                acc[mi][ni] = __builtin_amdgcn_mfma_f32_16x16x32_bf16(aF[mi], bF[ni], acc[mi][ni], 0, 0, 0);
    }
    __syncthreads();   // frags consumed; reuse LDS for output tile

    {
        const int mloc = wm * 64 + quad * 4;
        const int nloc = wn * 64 + l15;
        #pragma unroll
        for (int mi = 0; mi < 4; ++mi)
            #pragma unroll
            for (int r = 0; r < 4; ++r) {
                unsigned short* dst = &sm.ot[(mloc + mi * 16 + r) * 132 + nloc];
                #pragma unroll
                for (int ni = 0; ni < 4; ++ni)
                    dst[ni * 16] = f2bf(acc[mi][ni][r]);
            }
    }
    __syncthreads();

    #pragma unroll
    for (int i = 0; i < 8; ++i) {
        int cid = i * 256 + tid;
        int row = cid >> 4, ch = cid & 15;
        us8 v = *reinterpret_cast<const us8*>(&sm.ot[row * 132 + ch * 8]);
        *reinterpret_cast<us8*>(T + (size_t)(mt * 128 + row) * BN + (size_t)nt * 128 + ch * 8) = v;
    }
}

// ---- K2: LDS-staged (bf16) 36-tap gather + maxpool3 + bias + BN stats ----
// grid (o=128, b=64), 512 thr, 2 outputs/thread (p and p+16). LDS: 9 planes
// of 33 rows x 48 bf16 (8-col pads both sides, row 32 = zeros).
#define PLSB (33 * 48)

template<int RH, int RW>
__device__ __forceinline__ float gather_half(const unsigned short* __restrict__ lt,
                                             int p, int qoff,
                                             int g0, int g2, int f0, int f2) {
    // per-y3 / per-x3 selector patterns, keyed by (d mod 3):
    //   sel0[t] = floordiv3(t-d)-floordiv3(-d), sel2[t] = floordiv3(t+d)-floordiv3(d)
    constexpr int C0s[3][3] = {{0,0,0},{0,1,1},{0,0,1}};
    constexpr int C2s[3][3] = {{0,0,0},{0,0,1},{0,1,1}};
    constexpr int R0s[3][3] = {{0,0,0},{0,1,1},{0,0,1}};
    constexpr int R2s[3][3] = {{0,0,0},{0,0,1},{0,1,1}};
    constexpr int NR = RH ? 3 : 1;     // distinct row combos
    constexpr int NC = RW ? 3 : 1;     // distinct col combos
    constexpr bool RB = (RH != 0);     // need second-row variant at all?
    constexpr bool CB = (RW != 0);     // need b-columns at all?

    int rA0 = p + g0;     rA0 = ((unsigned)rA0 < 32u) ? rA0 : 32;
    int rA2 = p + g2;     rA2 = ((unsigned)rA2 < 32u) ? rA2 : 32;
    int rB0 = 0, rB2 = 0;
    if (RB) {
        rB0 = p + g0 + 1; rB0 = ((unsigned)rB0 < 32u) ? rB0 : 32;
        rB2 = p + g2 + 1; rB2 = ((unsigned)rB2 < 32u) ? rB2 : 32;
    }

    float u0[2][3], u1[3], u2[2][3];
    {   // ki = 0 (planes 0..2), rows rA0 (+rB0)
        const unsigned short* pl0 = &lt[0 * PLSB + qoff + f0];
        const unsigned short* pl1 = &lt[1 * PLSB + qoff];
        const unsigned short* pl2 = &lt[2 * PLSB + qoff + f2];
        float pA0a = bf2f(pl0[rA0 * 48]), pA0b = CB ? bf2f(pl0[rA0 * 48 + 1]) : 0.f;
        float sA   = bf2f(pl1[rA0 * 48]);
        float pA2a = bf2f(pl2[rA0 * 48]), pA2b = CB ? bf2f(pl2[rA0 * 48 + 1]) : 0.f;
        float pB0a = 0.f, pB0b = 0.f, sB = 0.f, pB2a = 0.f, pB2b = 0.f;
        if (RB) {
            pB0a = bf2f(pl0[rB0 * 48]); pB0b = CB ? bf2f(pl0[rB0 * 48 + 1]) : 0.f;
            sB   = bf2f(pl1[rB0 * 48]);
            pB2a = bf2f(pl2[rB0 * 48]); pB2b = CB ? bf2f(pl2[rB0 * 48 + 1]) : 0.f;
        }
        #pragma unroll
        for (int c = 0; c < NC; ++c) {
            u0[0][c] = (C0s[RW][c] ? pA0b : pA0a) + sA + (C2s[RW][c] ? pA2b : pA2a);
            if (RB)
                u0[1][c] = (C0s[RW][c] ? pB0b : pB0a) + sB + (C2s[RW][c] ? pB2b : pB2a);
        }
    }
    {   // ki = 1 (planes 3..5), row p only (selector identically 0)
        const unsigned short* pl0 = &lt[3 * PLSB + qoff + f0];
        const unsigned short* pl1 = &lt[4 * PLSB + qoff];
        const unsigned short* pl2 = &lt[5 * PLSB + qoff + f2];
        float pa = bf2f(pl0[p * 48]), pb = CB ? bf2f(pl0[p * 48 + 1]) : 0.f;
        float s  = bf2f(pl1[p * 48]);
        float ra = bf2f(pl2[p * 48]), rb = CB ? bf2f(pl2[p * 48 + 1]) : 0.f;
        #pragma unroll
        for (int c = 0; c < NC; ++c)
            u1[c] = (C0s[RW][c] ? pb : pa) + s + (C2s[RW][c] ? rb : ra);
    }
    {   // ki = 2 (planes 6..8), rows rA2 (+rB2)
        const unsigned short* pl0 = &lt[6 * PLSB + qoff + f0];
        const unsigned short* pl1 = &lt[7 * PLSB + qoff];
        const unsigned short* pl2 = &lt[8 * PLSB + qoff + f2];
        float pA0a = bf2f(pl0[rA2 * 48]), pA0b = CB ? bf2f(pl0[rA2 * 48 + 1]) : 0.f;
        float sA   = bf2f(pl1[rA2 * 48]);
        float pA2a = bf2f(pl2[rA2 * 48]), pA2b = CB ? bf2f(pl2[rA2 * 48 + 1]) : 0.f;
        float pB0a = 0.f, pB0b = 0.f, sB = 0.f, pB2a = 0.f, pB2b = 0.f;
        if (RB) {
            pB0a = bf2f(pl0[rB2 * 48]); pB0b = CB ? bf2f(pl0[rB2 * 48 + 1]) : 0.f;
            sB   = bf2f(pl1[rB2 * 48]);
            pB2a = bf2f(pl2[rB2 * 48]); pB2b = CB ? bf2f(pl2[rB2 * 48 + 1]) : 0.f;
        }
        #pragma unroll
        for (int c = 0; c < NC; ++c) {
            u2[0][c] = (C0s[RW][c] ? pA0b : pA0a) + sA + (C2s[RW][c] ? pA2b : pA2a);
            if (RB)
                u2[1][c] = (C0s[RW][c] ? pB0b : pB0a) + sB + (C2s[RW][c] ? pB2b : pB2a);
        }
    }

    float best = -3.4e38f;
    #pragma unroll
    for (int r = 0; r < NR; ++r)
        #pragma unroll
        for (int c = 0; c < NC; ++c) {
            float s = u0[R0s[RH][r]][c] + u1[c] + u2[R2s[RH][r]][c];
            best = fmaxf(best, s);
        }
    return best;
}

// O16: write pre-BN vals as bf16 to scratch (k3 converts); else f32 to out.
template<bool O16>
__global__ __launch_bounds__(512) void k2_gather(const unsigned short* __restrict__ T,
                                                 const float* __restrict__ bias,
                                                 const int* __restrict__ prm,
                                                 void* __restrict__ outv,
                                                 float* __restrict__ stats) {
    __shared__ __align__(16) unsigned short lt[9 * PLSB + 8];
    __shared__ float red[16];
    const int tid = threadIdx.x;
    const int o = blockIdx.x, b = blockIdx.y;

    // zero pad columns: 9 planes x 32 rows x 2 sides, one us8 (8 bf16) each.
    static const us8 z8 = {0, 0, 0, 0, 0, 0, 0, 0};
    {
        int i = tid;                               // 0..511
        int kk = i >> 6, rem = i & 63, r = rem >> 1, side = rem & 1;
        *reinterpret_cast<us8*>(&lt[kk * PLSB + r * 48 + side * 40]) = z8;
        if (tid < 64) {
            i = tid + 512;                         // 512..575
            kk = i >> 6; rem = i & 63; r = rem >> 1; side = rem & 1;
            *reinterpret_cast<us8*>(&lt[kk * PLSB + r * 48 + side * 40]) = z8;
        }
    }
    // zero row 32 of each plane: 9 x 48 bf16 = 54 us8; plus 8-el slack.
    if (tid < 54) {
        int kk = tid / 6, c = tid - kk * 6;
        *reinterpret_cast<us8*>(&lt[kk * PLSB + 32 * 48 + c * 8]) = z8;
    }
    if (tid == 63) *reinterpret_cast<us8*>(&lt[9 * PLSB]) = z8;

    // stage 9 planes (1024 bf16 contiguous each) -> bf16 padded rows (pure copy)
    const unsigned short* Tb = T + (size_t)o * BN + (size_t)b * 1024;
    {
        int i = tid;                               // pass 1: 0..511
        int kk = i >> 7, c8 = i & 127;
        us8 v = *reinterpret_cast<const us8*>(Tb + (size_t)kk * (128 * BN) + c8 * 8);
        *reinterpret_cast<us8*>(&lt[kk * PLSB + (c8 >> 2) * 48 + 8 + (c8 & 3) * 8]) = v;
        i = tid + 512;                             // pass 2: 512..1023
        kk = i >> 7; c8 = i & 127;
        us8 v2 = *reinterpret_cast<const us8*>(Tb + (size_t)kk * (128 * BN) + c8 * 8);
        *reinterpret_cast<us8*>(&lt[kk * PLSB + (c8 >> 2) * 48 + 8 + (c8 & 3) * 8]) = v2;
        if (tid < 128) {                           // pass 3: 1024..1151 (kk = 8)
            c8 = tid;
            us8 v3 = *reinterpret_cast<const us8*>(Tb + (size_t)8 * (128 * BN) + c8 * 8);
            *reinterpret_cast<us8*>(&lt[8 * PLSB + (c8 >> 2) * 48 + 8 + (c8 & 3) * 8]) = v3;
        }
    }
    __syncthreads();

    // block-uniform gather params (precomputed in k0, scalar loads)
    const int* pb = prm + b * 8;
    const int g0 = pb[0], g2 = pb[1], f0 = pb[2], f2 = pb[3], cs = pb[4];
    const int q = tid & 31, pbase = tid >> 5;   // pbase 0..15
    const int qoff = q + 8;
    const float bias_o = bias[o];

    float v0 = 0.f, v1 = 0.f;
    #define GCASE(n) case n: \
        v0 = gather_half<(n)/3, (n)%3>(lt, pbase,      qoff, g0, g2, f0, f2); \
        v1 = gather_half<(n)/3, (n)%3>(lt, pbase + 16, qoff, g0, g2, f0, f2); \
        break;
    switch (cs) {
        GCASE(0) GCASE(1) GCASE(2) GCASE(3)
        GCASE(4) GCASE(5) GCASE(6) GCASE(7)
        default:
            v0 = gather_half<2, 2>(lt, pbase,      qoff, g0, g2, f0, f2);
            v1 = gather_half<2, 2>(lt, pbase + 16, qoff, g0, g2, f0, f2);
            break;
    }
    #undef GCASE

    float val0 = v0 + bias_o;
    float val1 = v1 + bias_o;
    const size_t idx0 = (((size_t)b * 128 + o) * 32 + pbase) * 32 + q;
    const size_t idx1 = idx0 + 16 * 32;
    if (O16) {
        unsigned short* tout = (unsigned short*)outv;
        tout[idx0] = f2bf(val0);
        tout[idx1] = f2bf(val1);
    } else {
        float* out = (float*)outv;
        out[idx0] = val0;
        out[idx1] = val1;
    }
    float s1 = val0 + val1;
    float s2 = val0 * val0 + val1 * val1;

    // stats: wave reduce -> LDS -> block reduce -> 2 atomics
    #pragma unroll
    for (int m = 32; m >= 1; m >>= 1) {
        s1 += __shfl_xor(s1, m, 64);
        s2 += __shfl_xor(s2, m, 64);
    }
    if ((tid & 63) == 0) {
        red[tid >> 6] = s1;
        red[8 + (tid >> 6)] = s2;
    }
    __syncthreads();
    if (tid < 64) {
        float a1 = (tid < 8) ? red[tid] : 0.f;
        float a2 = (tid < 8) ? red[8 + tid] : 0.f;
        #pragma unroll
        for (int m = 4; m >= 1; m >>= 1) {
            a1 += __shfl_xor(a1, m, 64);
            a2 += __shfl_xor(a2, m, 64);
        }
        if (tid == 0) {
            atomicAdd(&stats[o], a1);
            atomicAdd(&stats[128 + o], a2);
        }
    }
}

// ---- K3a: BN finalize + affine + relu, bf16 scratch -> f32 out -----------
__global__ __launch_bounds__(256) void k3_bn_cvt(const us4* __restrict__ tin,
                                                 float4* __restrict__ out,
                                                 const float* __restrict__ stats,
                                                 const float* __restrict__ gamma,
                                                 const float* __restrict__ beta) {
    int i4 = blockIdx.x * 256 + threadIdx.x;   // 0..2097151
    int o = (i4 >> 8) & 127;
    const float invN = 1.0f / 65536.0f;
    float mean = stats[o] * invN;
    float var = stats[128 + o] * invN - mean * mean;
    float inv = rsqrtf(var + 1e-5f);
    float sc = gamma[o] * inv;
    float sh = beta[o] - mean * sc;
    us4 t = tin[i4];
    float4 v;
    v.x = fmaxf(fmaf(bf2f(t[0]), sc, sh), 0.f);
    v.y = fmaxf(fmaf(bf2f(t[1]), sc, sh), 0.f);
    v.z = fmaxf(fmaf(bf2f(t[2]), sc, sh), 0.f);
    v.w = fmaxf(fmaf(bf2f(t[3]), sc, sh), 0.f);
    out[i4] = v;
}

// ---- K3b: BN finalize + affine + relu, in-place on d_out (fallback) ------
__global__ __launch_bounds__(256) void k3_bn(float4* __restrict__ out,
                                             const float* __restrict__ stats,
                                             const float* __restrict__ gamma,
                                             const float* __restrict__ beta) {
    int i4 = blockIdx.x * 256 + threadIdx.x;   // 0..2097151
    int o = (i4 >> 8) & 127;
    const float invN = 1.0f / 65536.0f;
    float mean = stats[o] * invN;
    float var = stats[128 + o] * invN - mean * mean;
    float inv = rsqrtf(var + 1e-5f);
    float sc = gamma[o] * inv;
    float sh = beta[o] - mean * sc;
    float4 v = out[i4];
    v.x = fmaxf(fmaf(v.x, sc, sh), 0.f);
    v.y = fmaxf(fmaf(v.y, sc, sh), 0.f);
    v.z = fmaxf(fmaf(v.z, sc, sh), 0.f);
    v.w = fmaxf(fmaf(v.w, sc, sh), 0.f);
    out[i4] = v;
}

extern "C" void kernel_launch(void* const* d_in, const int* in_sizes, int n_in,
                              void* d_out, int out_size, void* d_ws, size_t ws_size,
                              hipStream_t stream) {
    const float* x     = (const float*)d_in[0];
    const int*   h     = (const int*)d_in[1];
    const int*   w     = (const int*)d_in[2];
    const float* wt    = (const float*)d_in[3];
    const float* bias  = (const float*)d_in[4];
    const float* gamma = (const float*)d_in[5];
    const float* beta  = (const float*)d_in[6];
    float* out = (float*)d_out;
    char* ws = (char*)d_ws;

    float*          stats = (float*)(ws + 0);
    int*            prm   = (int*)(ws + 1024);
    unsigned short* A     = (unsigned short*)(ws + 4096);
    unsigned short* XbT   = (unsigned short*)(ws + 151552);
    unsigned short* T     = (unsigned short*)(ws + 8540160);
    unsigned short* tout  = (unsigned short*)(ws + 159535104);   // 16.8MB scratch

    k0_all<<<1313, 256, 0, stream>>>(x, wt, h, w, XbT, A, stats, prm);
    k1_gemm<<<dim3(512, 9), 256, 0, stream>>>(XbT, A, T);

    const size_t need = 159535104ull + 16777216ull;   // T end + bf16 out scratch
    if (ws_size >= need) {
        k2_gather<true><<<dim3(128, 64), 512, 0, stream>>>(T, bias, prm, (void*)tout, stats);
        k3_bn_cvt<<<8192, 256, 0, stream>>>((const us4*)tout, (float4*)out, stats, gamma, beta);
    } else {
        k2_gather<false><<<dim3(128, 64), 512, 0, stream>>>(T, bias, prm, (void*)out, stats);
        k3_bn<<<8192, 256, 0, stream>>>((float4*)out, stats, gamma, beta);
    }
}